// Round 10
// baseline (105.431 us; speedup 1.0000x reference)
//
#include <hip/hip_runtime.h>

#define DIM 192
#define NB 8
#define NTOK 1024
#define HEADS 16
#define DH 64
#define INNER 1024
#define ROWS (NB * NTOK)  // 8192

typedef __bf16 bf16x8 __attribute__((ext_vector_type(8)));
typedef float f32x4 __attribute__((ext_vector_type(4)));
typedef float f32x16 __attribute__((ext_vector_type(16)));
typedef unsigned int u32x4 __attribute__((ext_vector_type(4)));

__device__ inline unsigned short f2bf(float f) {
    union { float f; unsigned u; } v; v.f = f;
    unsigned r = v.u + 0x7FFF + ((v.u >> 16) & 1);
    return (unsigned short)(r >> 16);
}

__device__ inline unsigned pk2(float a, float b) {
    __bf16 x = (__bf16)a, y = (__bf16)b;
    unsigned short ux = __builtin_bit_cast(unsigned short, x);
    unsigned short uy = __builtin_bit_cast(unsigned short, y);
    return (unsigned)ux | ((unsigned)uy << 16);
}

// async global->LDS, 16B per lane; dest must be wave-linear (base + lane*16)
__device__ inline void gl_lds16(const unsigned short* g, unsigned short* l) {
    __builtin_amdgcn_global_load_lds(
        (const __attribute__((address_space(1))) void*)g,
        (__attribute__((address_space(3))) void*)l, 16, 0, 0);
}

// fragment-major index for a [*][depth] bf16 operand consumed as 32x32x16
__device__ inline size_t fragIdx(int row, int k, int depth) {
    return ((size_t)(row >> 5) * ((size_t)depth * 4) +
            (size_t)(((k >> 4) * 2 + ((k >> 3) & 1)) * 32 + (row & 31))) * 8 + (k & 7);
}

// ---------------- fused preprocessing ----------------
__global__ __launch_bounds__(256) void k_pre(
    const float* __restrict__ x, const float* __restrict__ shift,
    const float* __restrict__ scale, const float* __restrict__ nw,
    const float* __restrict__ nb, const float* __restrict__ wqkv,
    const float* __restrict__ wout,
    unsigned short* __restrict__ hF, unsigned short* __restrict__ wF,
    unsigned short* __restrict__ woF) {
    int bid = blockIdx.x;
    if (bid < 2048) {
        int row = bid * 4 + (threadIdx.x >> 6);
        int lane = threadIdx.x & 63;
        const float* xr = x + row * DIM;
        float v0 = xr[lane], v1 = xr[lane + 64], v2 = xr[lane + 128];
        float s = v0 + v1 + v2;
        #pragma unroll
        for (int m = 1; m < 64; m <<= 1) s += __shfl_xor(s, m);
        float mean = s * (1.0f / DIM);
        float d0 = v0 - mean, d1 = v1 - mean, d2 = v2 - mean;
        float q = d0 * d0 + d1 * d1 + d2 * d2;
        #pragma unroll
        for (int m = 1; m < 64; m <<= 1) q += __shfl_xor(q, m);
        float rs = rsqrtf(q * (1.0f / DIM) + 1e-5f);
        int b = row >> 10;
        float vv[3] = {v0, v1, v2};
        #pragma unroll
        for (int i = 0; i < 3; i++) {
            int d = lane + 64 * i;
            float val = (vv[i] - mean) * rs * nw[d] + nb[d];
            val = val * (1.0f + scale[b * DIM + d]) + shift[b * DIM + d];
            hF[fragIdx(row, d, DIM)] = f2bf(val);
        }
    } else if (bid < 4352) {
        int idx = (bid - 2048) * 256 + threadIdx.x;  // < 192*3072
        int k = idx / 3072, c = idx % 3072;
        wF[fragIdx(c, k, DIM)] = f2bf(wqkv[idx]);
    } else {
        int idx = (bid - 4352) * 256 + threadIdx.x;  // < 1024*192
        int k = idx / 192, c = idx % 192;
        woF[fragIdx(c, k, INNER)] = f2bf(wout[idx]);
    }
}

// ---------------- QKV GEMM v3: fragment-major, LDS-free ----------------
// Q is pre-scaled by 0.125*log2(e) so k_attn's softmax is exp2(C) directly.
__global__ __launch_bounds__(256, 3) void k_qkv(
    const unsigned short* __restrict__ hF, const unsigned short* __restrict__ wF,
    unsigned short* __restrict__ qm, unsigned short* __restrict__ km,
    unsigned short* __restrict__ vtm) {
    const float QSC = 0.125f * 1.4426950408889634f;
    int tid = threadIdx.x;
    int wave = tid >> 6, lane = tid & 63;
    int l31 = lane & 31, hi = lane >> 5;
    int c0 = blockIdx.x * 64 + (wave >> 1) * 32;
    int typ = c0 >> 10;              // 0=Q 1=K 2=V
    int hd  = (c0 & 1023) >> 6;      // head
    int coff = c0 & 32;              // c-tile offset within head-panel

    const unsigned short* Ab = wF + (size_t)(c0 >> 5) * 768 * 8;
    bf16x8 af[12];
    #pragma unroll
    for (int kc = 0; kc < 12; kc++)
        af[kc] = *(const bf16x8*)(Ab + ((kc * 2 + hi) * 32 + l31) * 8);

    #pragma unroll
    for (int ns = 0; ns < 2; ns++) {
        int n0 = blockIdx.y * 128 + (wave & 1) * 64 + ns * 32;
        const unsigned short* Bb = hF + (size_t)(n0 >> 5) * 768 * 8;
        f32x16 acc;
        #pragma unroll
        for (int r = 0; r < 16; r++) acc[r] = 0.f;
        #pragma unroll
        for (int kc = 0; kc < 12; kc++) {
            bf16x8 bf = *(const bf16x8*)(Bb + ((kc * 2 + hi) * 32 + l31) * 8);
            acc = __builtin_amdgcn_mfma_f32_32x32x16_bf16(af[kc], bf, acc, 0, 0, 0);
        }
        int n = n0 + l31, bb = n >> 10, nm = n & 1023;
        if (typ < 2) {
            float sc = (typ == 0) ? QSC : 1.0f;
            unsigned short* base = (typ == 0 ? qm : km) +
                ((size_t)(bb * 16 + hd) * 1024 + nm) * 64;
            #pragma unroll
            for (int rg = 0; rg < 4; rg++) {
                uint2 val;
                val.x = pk2(acc[rg * 4 + 0] * sc, acc[rg * 4 + 1] * sc);
                val.y = pk2(acc[rg * 4 + 2] * sc, acc[rg * 4 + 3] * sc);
                *(uint2*)(base + coff + rg * 8 + hi * 4) = val;
            }
        } else {
            unsigned short* base = vtm + (size_t)(bb * 16 + hd) * 65536 + nm;
            #pragma unroll
            for (int r = 0; r < 16; r++) {
                int d = coff + (r & 3) + 8 * (r >> 2) + 4 * hi;
                base[(size_t)d * 1024] = f2bf(acc[r]);
            }
        }
    }
}

// ---------------- flash attention v6: counted-vmcnt pipeline + l-via-MFMA ----------------
// grid (128 bh, 4 qt) x 512 thr (8 waves). Wave owns 32 q-rows; KVBLK=64.
// Zero-max softmax (P = exp2(C), scores bounded << fp32 exp2 range).
// T4: raw s_barrier + counted vmcnt; K prefetch distance 2, V distance 1,
// both triple-buffered; stages issued AFTER the barrier (recycled slot's
// readers finished before it). Wait schedule (derived, see journal):
//   prologue issues [K0,V0,K1]; t=0 -> vmcnt(1); t in [1,14] -> vmcnt(2);
//   t=15 -> vmcnt(1); epilogue -> vmcnt(0)+barrier.
// l computed by mfma(ones, pw, accL): replaces 32-deep serial add chain;
// numerator and denominator share the same bf16-rounded P.
__global__ __launch_bounds__(512, 4) void k_attn(
    const unsigned short* __restrict__ qm, const unsigned short* __restrict__ km,
    const unsigned short* __restrict__ vtm, unsigned short* __restrict__ attnF) {
    __shared__ __align__(128) unsigned short Kb[3][4096];
    __shared__ __align__(128) unsigned short Vb[3][4096];

    int tid = threadIdx.x;
    int wave = tid >> 6, lane = tid & 63;
    int l31 = lane & 31, hi = lane >> 5;
    int bh = blockIdx.x, qt = blockIdx.y;
    int qbase = qt * 256 + wave * 32;
    const unsigned short* Q = qm + (size_t)bh * NTOK * DH;
    const unsigned short* K = km + (size_t)bh * NTOK * DH;
    const unsigned short* VT = vtm + (size_t)bh * DH * NTOK;

    bf16x8 qf[4];
    #pragma unroll
    for (int c = 0; c < 4; c++)
        qf[c] = *(const bf16x8*)(Q + (qbase + l31) * DH + c * 16 + hi * 8);

    u32x4 ov; ov[0] = 0x3F803F80u; ov[1] = 0x3F803F80u; ov[2] = 0x3F803F80u; ov[3] = 0x3F803F80u;
    bf16x8 ones = __builtin_bit_cast(bf16x8, ov);

    f32x16 accO[2], accL;
    #pragma unroll
    for (int r = 0; r < 16; r++) { accO[0][r] = 0.f; accO[1][r] = 0.f; accL[r] = 0.f; }

    auto stageK = [&](int slot, int t) {
        int off = tid * 16;
        int row = off >> 7, col = off & 127;
        int scol = col ^ ((row & 7) << 4);
        gl_lds16(K + (t * 64 + row) * DH + (scol >> 1),
                 (unsigned short*)((char*)Kb[slot] + off));
    };
    auto stageV = [&](int slot, int t) {
        int off = tid * 16;
        int row = off >> 7, col = off & 127;
        int scol = col ^ ((row & 7) << 4);
        gl_lds16(VT + (size_t)row * NTOK + t * 64 + (scol >> 1),
                 (unsigned short*)((char*)Vb[slot] + off));
    };
    auto ldK = [&](int slot, int row, int col) -> bf16x8 {
        int scol = col ^ ((row & 7) << 4);
        return *(const bf16x8*)((const char*)Kb[slot] + row * 128 + scol);
    };
    auto ldV = [&](int slot, int row, int col) -> bf16x8 {
        int scol = col ^ ((row & 7) << 4);
        return *(const bf16x8*)((const char*)Vb[slot] + row * 128 + scol);
    };
    auto packP = [&](const f32x16& P, bf16x8& w0, bf16x8& w1) {
        u32x4 A, B;
        {
            auto r0 = __builtin_amdgcn_permlane32_swap(pk2(P[0], P[1]), pk2(P[4], P[5]), false, false);
            auto r1 = __builtin_amdgcn_permlane32_swap(pk2(P[2], P[3]), pk2(P[6], P[7]), false, false);
            A[0] = r0[0]; A[1] = r1[0]; A[2] = r0[1]; A[3] = r1[1];
        }
        {
            auto r0 = __builtin_amdgcn_permlane32_swap(pk2(P[8], P[9]), pk2(P[12], P[13]), false, false);
            auto r1 = __builtin_amdgcn_permlane32_swap(pk2(P[10], P[11]), pk2(P[14], P[15]), false, false);
            B[0] = r0[0]; B[1] = r1[0]; B[2] = r0[1]; B[3] = r1[1];
        }
        w0 = __builtin_bit_cast(bf16x8, A);
        w1 = __builtin_bit_cast(bf16x8, B);
    };

    bf16x8 pw[4];

    // prologue, exact issue order K0, V0, K1 (wait counts depend on it)
    stageK(0, 0);
    stageV(0, 0);
    stageK(1, 1);

    #pragma unroll 1
    for (int t = 0; t < 16; t++) {
        if (t == 0 || t == 15) {
            asm volatile("s_waitcnt vmcnt(1)" ::: "memory");
        } else {
            asm volatile("s_waitcnt vmcnt(2)" ::: "memory");
        }
        __builtin_amdgcn_s_barrier();
        __builtin_amdgcn_sched_barrier(0);

        if (t <= 13) stageK((t + 2) % 3, t + 2);
        if (t <= 14) stageV((t + 1) % 3, t + 1);

        int ks = t % 3;
        f32x16 C0, C1;
        #pragma unroll
        for (int r = 0; r < 16; r++) { C0[r] = 0.f; C1[r] = 0.f; }
        __builtin_amdgcn_s_setprio(1);
        #pragma unroll
        for (int c = 0; c < 4; c++) {
            bf16x8 kf = ldK(ks, l31, c * 32 + hi * 16);
            C0 = __builtin_amdgcn_mfma_f32_32x32x16_bf16(kf, qf[c], C0, 0, 0, 0);
            bf16x8 kf2 = ldK(ks, 32 + l31, c * 32 + hi * 16);
            C1 = __builtin_amdgcn_mfma_f32_32x32x16_bf16(kf2, qf[c], C1, 0, 0, 0);
        }
        if (t >= 1) {
            int vs = (t - 1) % 3;
            #pragma unroll
            for (int dt = 0; dt < 2; dt++) {
                #pragma unroll
                for (int kcc = 0; kcc < 4; kcc++) {
                    bf16x8 vf = ldV(vs, dt * 32 + l31, kcc * 32 + hi * 16);
                    accO[dt] = __builtin_amdgcn_mfma_f32_32x32x16_bf16(vf, pw[kcc], accO[dt], 0, 0, 0);
                }
            }
        }
        __builtin_amdgcn_s_setprio(0);

        #pragma unroll
        for (int r = 0; r < 16; r++) {
            C0[r] = __builtin_amdgcn_exp2f(C0[r]);
            C1[r] = __builtin_amdgcn_exp2f(C1[r]);
        }
        packP(C0, pw[0], pw[1]);
        packP(C1, pw[2], pw[3]);
        #pragma unroll
        for (int kcc = 0; kcc < 4; kcc++)
            accL = __builtin_amdgcn_mfma_f32_32x32x16_bf16(ones, pw[kcc], accL, 0, 0, 0);
    }

    // epilogue: PV(15); V(15) lives in Vb[15%3 == 0]
    asm volatile("s_waitcnt vmcnt(0)" ::: "memory");
    __builtin_amdgcn_s_barrier();
    __builtin_amdgcn_sched_barrier(0);
    __builtin_amdgcn_s_setprio(1);
    #pragma unroll
    for (int dt = 0; dt < 2; dt++) {
        #pragma unroll
        for (int kcc = 0; kcc < 4; kcc++) {
            bf16x8 vf = ldV(0, dt * 32 + l31, kcc * 32 + hi * 16);
            accO[dt] = __builtin_amdgcn_mfma_f32_32x32x16_bf16(vf, pw[kcc], accO[dt], 0, 0, 0);
        }
    }
    __builtin_amdgcn_s_setprio(0);
    #pragma unroll
    for (int kcc = 0; kcc < 4; kcc++)
        accL = __builtin_amdgcn_mfma_f32_32x32x16_bf16(ones, pw[kcc], accL, 0, 0, 0);
    // note: tile15's pw contributed to accL inside the loop already? No —
    // loop iter 15 packed pw(15) and ran accL on it. The 4 MFMAs above would
    // double-count. Remove them: (kept as comment for the journal)
    #pragma unroll
    for (int kcc = 0; kcc < 4; kcc++) {
        // undo the double-count: subtract via mfma with negated ones
        u32x4 nv; nv[0] = 0xBF80BF80u; nv[1] = 0xBF80BF80u; nv[2] = 0xBF80BF80u; nv[3] = 0xBF80BF80u;
        bf16x8 nones = __builtin_bit_cast(bf16x8, nv);
        accL = __builtin_amdgcn_mfma_f32_32x32x16_bf16(nones, pw[kcc], accL, 0, 0, 0);
    }

    float l = accL[0];
    float inv = 1.0f / l;
    int b = bh >> 4, hd = bh & 15;
    int rowblk = b * 32 + qt * 8 + wave;
    #pragma unroll
    for (int dt = 0; dt < 2; dt++)
        #pragma unroll
        for (int rq = 0; rq < 4; rq++) {
            int g = (hd * 4 + dt * 2 + (rq >> 1)) * 2 + (rq & 1);
            uint2 val;
            val.x = pk2(accO[dt][rq * 4 + 0] * inv, accO[dt][rq * 4 + 1] * inv);
            val.y = pk2(accO[dt][rq * 4 + 2] * inv, accO[dt][rq * 4 + 3] * inv);
            *(uint2*)((char*)attnF + ((size_t)rowblk * 4096 + g * 32 + l31) * 16 + hi * 8) = val;
        }
}

// ---------------- out projection v2: fragment-major, LDS-free ----------------
__global__ __launch_bounds__(256, 2) void k_out(
    const unsigned short* __restrict__ attnF, const unsigned short* __restrict__ woF,
    const float* __restrict__ bias, float* __restrict__ out) {
    int wave = threadIdx.x >> 6, lane = threadIdx.x & 63;
    int l31 = lane & 31, hi = lane >> 5;
    int W = blockIdx.x * 4 + wave;   // 0..1535
    int nb = W / 6, cb = W % 6;      // 256 n-blocks x 6 c-blocks
    const unsigned short* A = attnF + (size_t)nb * 4096 * 8;
    const unsigned short* B = woF + (size_t)cb * 4096 * 8;

    f32x16 acc;
    #pragma unroll
    for (int r = 0; r < 16; r++) acc[r] = 0.f;
    #pragma unroll 16
    for (int kc = 0; kc < 64; kc++) {
        bf16x8 a = *(const bf16x8*)(A + ((kc * 2 + hi) * 32 + l31) * 8);
        bf16x8 b = *(const bf16x8*)(B + ((kc * 2 + hi) * 32 + l31) * 8);
        acc = __builtin_amdgcn_mfma_f32_32x32x16_bf16(a, b, acc, 0, 0, 0);
    }
    float bi = bias[cb * 32 + l31];
    #pragma unroll
    for (int r = 0; r < 16; r++) {
        int n = nb * 32 + (r & 3) + 8 * (r >> 2) + 4 * hi;
        out[(size_t)n * DIM + cb * 32 + l31] = acc[r] + bi;
    }
}

extern "C" void kernel_launch(void* const* d_in, const int* in_sizes, int n_in,
                              void* d_out, int out_size, void* d_ws, size_t ws_size,
                              hipStream_t stream) {
    const float* x     = (const float*)d_in[0];
    const float* shift = (const float*)d_in[1];
    const float* scale = (const float*)d_in[2];
    const float* nw    = (const float*)d_in[3];
    const float* nbv   = (const float*)d_in[4];
    const float* wqkv  = (const float*)d_in[5];
    const float* wout  = (const float*)d_in[6];
    const float* bout  = (const float*)d_in[7];
    float* out = (float*)d_out;

    char* ws = (char*)d_ws;
    unsigned short* hF    = (unsigned short*)(ws + 0);
    unsigned short* wF    = (unsigned short*)(ws + 3145728);
    unsigned short* woF   = (unsigned short*)(ws + 3145728 + 1179648);
    unsigned short* qm    = (unsigned short*)(ws + 4718592);
    unsigned short* km    = (unsigned short*)(ws + 4718592 + 16777216);
    unsigned short* vtm   = (unsigned short*)(ws + 4718592 + 2 * 16777216);
    unsigned short* attnF = (unsigned short*)(ws + 4718592 + 3 * 16777216);

    k_pre<<<dim3(5120), dim3(256), 0, stream>>>(x, shift, scale, nw, nbv, wqkv, wout, hF, wF, woF);
    k_qkv<<<dim3(48, 64), dim3(256), 0, stream>>>(hF, wF, qm, km, vtm);
    k_attn<<<dim3(128, 4), dim3(512), 0, stream>>>(qm, km, vtm, attnF);
    k_out<<<dim3(384), dim3(256), 0, stream>>>(attnF, woF, bout, out);
}

// Round 11
// 99.993 us; speedup vs baseline: 1.0544x; 1.0544x over previous
//
#include <hip/hip_runtime.h>

#define DIM 192
#define NB 8
#define NTOK 1024
#define HEADS 16
#define DH 64
#define INNER 1024
#define ROWS (NB * NTOK)  // 8192

typedef __bf16 bf16x8 __attribute__((ext_vector_type(8)));
typedef float f32x4 __attribute__((ext_vector_type(4)));
typedef float f32x16 __attribute__((ext_vector_type(16)));
typedef unsigned int u32x4 __attribute__((ext_vector_type(4)));

__device__ inline unsigned short f2bf(float f) {
    union { float f; unsigned u; } v; v.f = f;
    unsigned r = v.u + 0x7FFF + ((v.u >> 16) & 1);
    return (unsigned short)(r >> 16);
}

__device__ inline unsigned pk2(float a, float b) {
    __bf16 x = (__bf16)a, y = (__bf16)b;
    unsigned short ux = __builtin_bit_cast(unsigned short, x);
    unsigned short uy = __builtin_bit_cast(unsigned short, y);
    return (unsigned)ux | ((unsigned)uy << 16);
}

// async global->LDS, 16B per lane; dest must be wave-linear (base + lane*16)
__device__ inline void gl_lds16(const unsigned short* g, unsigned short* l) {
    __builtin_amdgcn_global_load_lds(
        (const __attribute__((address_space(1))) void*)g,
        (__attribute__((address_space(3))) void*)l, 16, 0, 0);
}

// fragment-major index for a [*][depth] bf16 operand consumed as 32x32x16
__device__ inline size_t fragIdx(int row, int k, int depth) {
    return ((size_t)(row >> 5) * ((size_t)depth * 4) +
            (size_t)(((k >> 4) * 2 + ((k >> 3) & 1)) * 32 + (row & 31))) * 8 + (k & 7);
}

// ---------------- fused preprocessing ----------------
__global__ __launch_bounds__(256) void k_pre(
    const float* __restrict__ x, const float* __restrict__ shift,
    const float* __restrict__ scale, const float* __restrict__ nw,
    const float* __restrict__ nb, const float* __restrict__ wqkv,
    const float* __restrict__ wout,
    unsigned short* __restrict__ hF, unsigned short* __restrict__ wF,
    unsigned short* __restrict__ woF) {
    int bid = blockIdx.x;
    if (bid < 2048) {
        int row = bid * 4 + (threadIdx.x >> 6);
        int lane = threadIdx.x & 63;
        const float* xr = x + row * DIM;
        float v0 = xr[lane], v1 = xr[lane + 64], v2 = xr[lane + 128];
        float s = v0 + v1 + v2;
        #pragma unroll
        for (int m = 1; m < 64; m <<= 1) s += __shfl_xor(s, m);
        float mean = s * (1.0f / DIM);
        float d0 = v0 - mean, d1 = v1 - mean, d2 = v2 - mean;
        float q = d0 * d0 + d1 * d1 + d2 * d2;
        #pragma unroll
        for (int m = 1; m < 64; m <<= 1) q += __shfl_xor(q, m);
        float rs = rsqrtf(q * (1.0f / DIM) + 1e-5f);
        int b = row >> 10;
        float vv[3] = {v0, v1, v2};
        #pragma unroll
        for (int i = 0; i < 3; i++) {
            int d = lane + 64 * i;
            float val = (vv[i] - mean) * rs * nw[d] + nb[d];
            val = val * (1.0f + scale[b * DIM + d]) + shift[b * DIM + d];
            hF[fragIdx(row, d, DIM)] = f2bf(val);
        }
    } else if (bid < 4352) {
        int idx = (bid - 2048) * 256 + threadIdx.x;  // < 192*3072
        int k = idx / 3072, c = idx % 3072;
        wF[fragIdx(c, k, DIM)] = f2bf(wqkv[idx]);
    } else {
        int idx = (bid - 4352) * 256 + threadIdx.x;  // < 1024*192
        int k = idx / 192, c = idx % 192;
        woF[fragIdx(c, k, INNER)] = f2bf(wout[idx]);
    }
}

// ---------------- QKV GEMM v3: fragment-major, LDS-free ----------------
// Q is pre-scaled by 0.125*log2(e) so k_attn's softmax is exp2(C) directly.
__global__ __launch_bounds__(256, 3) void k_qkv(
    const unsigned short* __restrict__ hF, const unsigned short* __restrict__ wF,
    unsigned short* __restrict__ qm, unsigned short* __restrict__ km,
    unsigned short* __restrict__ vtm) {
    const float QSC = 0.125f * 1.4426950408889634f;
    int tid = threadIdx.x;
    int wave = tid >> 6, lane = tid & 63;
    int l31 = lane & 31, hi = lane >> 5;
    int c0 = blockIdx.x * 64 + (wave >> 1) * 32;
    int typ = c0 >> 10;              // 0=Q 1=K 2=V
    int hd  = (c0 & 1023) >> 6;      // head
    int coff = c0 & 32;              // c-tile offset within head-panel

    const unsigned short* Ab = wF + (size_t)(c0 >> 5) * 768 * 8;
    bf16x8 af[12];
    #pragma unroll
    for (int kc = 0; kc < 12; kc++)
        af[kc] = *(const bf16x8*)(Ab + ((kc * 2 + hi) * 32 + l31) * 8);

    #pragma unroll
    for (int ns = 0; ns < 2; ns++) {
        int n0 = blockIdx.y * 128 + (wave & 1) * 64 + ns * 32;
        const unsigned short* Bb = hF + (size_t)(n0 >> 5) * 768 * 8;
        f32x16 acc;
        #pragma unroll
        for (int r = 0; r < 16; r++) acc[r] = 0.f;
        #pragma unroll
        for (int kc = 0; kc < 12; kc++) {
            bf16x8 bf = *(const bf16x8*)(Bb + ((kc * 2 + hi) * 32 + l31) * 8);
            acc = __builtin_amdgcn_mfma_f32_32x32x16_bf16(af[kc], bf, acc, 0, 0, 0);
        }
        int n = n0 + l31, bb = n >> 10, nm = n & 1023;
        if (typ < 2) {
            float sc = (typ == 0) ? QSC : 1.0f;
            unsigned short* base = (typ == 0 ? qm : km) +
                ((size_t)(bb * 16 + hd) * 1024 + nm) * 64;
            #pragma unroll
            for (int rg = 0; rg < 4; rg++) {
                uint2 val;
                val.x = pk2(acc[rg * 4 + 0] * sc, acc[rg * 4 + 1] * sc);
                val.y = pk2(acc[rg * 4 + 2] * sc, acc[rg * 4 + 3] * sc);
                *(uint2*)(base + coff + rg * 8 + hi * 4) = val;
            }
        } else {
            unsigned short* base = vtm + (size_t)(bb * 16 + hd) * 65536 + nm;
            #pragma unroll
            for (int r = 0; r < 16; r++) {
                int d = coff + (r & 3) + 8 * (r >> 2) + 4 * hi;
                base[(size_t)d * 1024] = f2bf(acc[r]);
            }
        }
    }
}

// ---------------- flash attention v7: round-9 structure + l-via-MFMA ----------------
// grid (128 bh, 4 qt) x 512 thr (8 waves). Wave owns 32 q-rows; KVBLK=64.
// Zero-max softmax (P = exp2(C)); __syncthreads pipeline (round-9, proven);
// l accumulated by mfma(ones, pw, accL) inside the loop (removes the 32-deep
// serial add chain; round 10 proved the mechanism: VALUBusy 45->38).
__global__ __launch_bounds__(512, 4) void k_attn(
    const unsigned short* __restrict__ qm, const unsigned short* __restrict__ km,
    const unsigned short* __restrict__ vtm, unsigned short* __restrict__ attnF) {
    __shared__ __align__(128) unsigned short Kb[2][4096];
    __shared__ __align__(128) unsigned short Vb[3][4096];

    int tid = threadIdx.x;
    int wave = tid >> 6, lane = tid & 63;
    int l31 = lane & 31, hi = lane >> 5;
    int bh = blockIdx.x, qt = blockIdx.y;
    int qbase = qt * 256 + wave * 32;
    const unsigned short* Q = qm + (size_t)bh * NTOK * DH;
    const unsigned short* K = km + (size_t)bh * NTOK * DH;
    const unsigned short* VT = vtm + (size_t)bh * DH * NTOK;

    bf16x8 qf[4];
    #pragma unroll
    for (int c = 0; c < 4; c++)
        qf[c] = *(const bf16x8*)(Q + (qbase + l31) * DH + c * 16 + hi * 8);

    u32x4 ov; ov[0] = 0x3F803F80u; ov[1] = 0x3F803F80u; ov[2] = 0x3F803F80u; ov[3] = 0x3F803F80u;
    bf16x8 ones = __builtin_bit_cast(bf16x8, ov);

    f32x16 accO[2], accL;
    #pragma unroll
    for (int r = 0; r < 16; r++) { accO[0][r] = 0.f; accO[1][r] = 0.f; accL[r] = 0.f; }

    auto stageK = [&](int b, int t) {
        int off = tid * 16;
        int row = off >> 7, col = off & 127;
        int scol = col ^ ((row & 7) << 4);
        gl_lds16(K + (t * 64 + row) * DH + (scol >> 1),
                 (unsigned short*)((char*)Kb[b] + off));
    };
    auto stageV = [&](int b, int t) {
        int off = tid * 16;
        int row = off >> 7, col = off & 127;
        int scol = col ^ ((row & 7) << 4);
        gl_lds16(VT + (size_t)row * NTOK + t * 64 + (scol >> 1),
                 (unsigned short*)((char*)Vb[b] + off));
    };
    auto ldK = [&](int b, int row, int col) -> bf16x8 {
        int scol = col ^ ((row & 7) << 4);
        return *(const bf16x8*)((const char*)Kb[b] + row * 128 + scol);
    };
    auto ldV = [&](int b, int row, int col) -> bf16x8 {
        int scol = col ^ ((row & 7) << 4);
        return *(const bf16x8*)((const char*)Vb[b] + row * 128 + scol);
    };
    auto packP = [&](const f32x16& P, bf16x8& w0, bf16x8& w1) {
        u32x4 A, B;
        {
            auto r0 = __builtin_amdgcn_permlane32_swap(pk2(P[0], P[1]), pk2(P[4], P[5]), false, false);
            auto r1 = __builtin_amdgcn_permlane32_swap(pk2(P[2], P[3]), pk2(P[6], P[7]), false, false);
            A[0] = r0[0]; A[1] = r1[0]; A[2] = r0[1]; A[3] = r1[1];
        }
        {
            auto r0 = __builtin_amdgcn_permlane32_swap(pk2(P[8], P[9]), pk2(P[12], P[13]), false, false);
            auto r1 = __builtin_amdgcn_permlane32_swap(pk2(P[10], P[11]), pk2(P[14], P[15]), false, false);
            B[0] = r0[0]; B[1] = r1[0]; B[2] = r0[1]; B[3] = r1[1];
        }
        w0 = __builtin_bit_cast(bf16x8, A);
        w1 = __builtin_bit_cast(bf16x8, B);
    };

    bf16x8 pw[4];

    stageK(0, 0); stageV(0, 0);
    __syncthreads();

    // ---- iter 0: QK(0), exp, pack, accL (no PV yet) ----
    stageK(1, 1); stageV(1, 1);
    {
        f32x16 C0, C1;
        #pragma unroll
        for (int r = 0; r < 16; r++) { C0[r] = 0.f; C1[r] = 0.f; }
        __builtin_amdgcn_s_setprio(1);
        #pragma unroll
        for (int c = 0; c < 4; c++) {
            bf16x8 kf = ldK(0, l31, c * 32 + hi * 16);
            C0 = __builtin_amdgcn_mfma_f32_32x32x16_bf16(kf, qf[c], C0, 0, 0, 0);
            bf16x8 kf2 = ldK(0, 32 + l31, c * 32 + hi * 16);
            C1 = __builtin_amdgcn_mfma_f32_32x32x16_bf16(kf2, qf[c], C1, 0, 0, 0);
        }
        __builtin_amdgcn_s_setprio(0);
        #pragma unroll
        for (int r = 0; r < 16; r++) {
            C0[r] = __builtin_amdgcn_exp2f(C0[r]);
            C1[r] = __builtin_amdgcn_exp2f(C1[r]);
        }
        packP(C0, pw[0], pw[1]);
        packP(C1, pw[2], pw[3]);
        #pragma unroll
        for (int kcc = 0; kcc < 4; kcc++)
            accL = __builtin_amdgcn_mfma_f32_32x32x16_bf16(ones, pw[kcc], accL, 0, 0, 0);
        __syncthreads();
    }

    // ---- steady state: QK(t) + PV(t-1) back-to-back, then exp/pack/accL ----
    for (int t = 1; t < 16; t++) {
        int kc = t & 1;
        int vp = (t - 1) % 3;
        if (t < 15) { stageK((t + 1) & 1, t + 1); stageV((t + 1) % 3, t + 1); }

        f32x16 C0, C1;
        #pragma unroll
        for (int r = 0; r < 16; r++) { C0[r] = 0.f; C1[r] = 0.f; }
        __builtin_amdgcn_s_setprio(1);
        #pragma unroll
        for (int c = 0; c < 4; c++) {
            bf16x8 kf = ldK(kc, l31, c * 32 + hi * 16);
            C0 = __builtin_amdgcn_mfma_f32_32x32x16_bf16(kf, qf[c], C0, 0, 0, 0);
            bf16x8 kf2 = ldK(kc, 32 + l31, c * 32 + hi * 16);
            C1 = __builtin_amdgcn_mfma_f32_32x32x16_bf16(kf2, qf[c], C1, 0, 0, 0);
        }
        // PV(t-1): independent of C(t); fills the MFMA pipe while exp waits
        #pragma unroll
        for (int dt = 0; dt < 2; dt++) {
            #pragma unroll
            for (int kcc = 0; kcc < 4; kcc++) {
                bf16x8 vf = ldV(vp, dt * 32 + l31, kcc * 32 + hi * 16);
                accO[dt] = __builtin_amdgcn_mfma_f32_32x32x16_bf16(vf, pw[kcc], accO[dt], 0, 0, 0);
            }
        }
        __builtin_amdgcn_s_setprio(0);

        #pragma unroll
        for (int r = 0; r < 16; r++) {
            C0[r] = __builtin_amdgcn_exp2f(C0[r]);
            C1[r] = __builtin_amdgcn_exp2f(C1[r]);
        }
        packP(C0, pw[0], pw[1]);
        packP(C1, pw[2], pw[3]);
        #pragma unroll
        for (int kcc = 0; kcc < 4; kcc++)
            accL = __builtin_amdgcn_mfma_f32_32x32x16_bf16(ones, pw[kcc], accL, 0, 0, 0);
        __syncthreads();
    }

    // ---- epilogue: PV(15); V(15) lives in Vb[15%3 == 0]; accL(15) done in-loop ----
    __builtin_amdgcn_s_setprio(1);
    #pragma unroll
    for (int dt = 0; dt < 2; dt++) {
        #pragma unroll
        for (int kcc = 0; kcc < 4; kcc++) {
            bf16x8 vf = ldV(0, dt * 32 + l31, kcc * 32 + hi * 16);
            accO[dt] = __builtin_amdgcn_mfma_f32_32x32x16_bf16(vf, pw[kcc], accO[dt], 0, 0, 0);
        }
    }
    __builtin_amdgcn_s_setprio(0);

    // l = accL[0] (every C/D row of mfma(ones,P^T) holds l(q=l31))
    float inv = 1.0f / accL[0];
    int b = bh >> 4, hd = bh & 15;
    int rowblk = b * 32 + qt * 8 + wave;
    #pragma unroll
    for (int dt = 0; dt < 2; dt++)
        #pragma unroll
        for (int rq = 0; rq < 4; rq++) {
            int g = (hd * 4 + dt * 2 + (rq >> 1)) * 2 + (rq & 1);
            uint2 val;
            val.x = pk2(accO[dt][rq * 4 + 0] * inv, accO[dt][rq * 4 + 1] * inv);
            val.y = pk2(accO[dt][rq * 4 + 2] * inv, accO[dt][rq * 4 + 3] * inv);
            *(uint2*)((char*)attnF + ((size_t)rowblk * 4096 + g * 32 + l31) * 16 + hi * 8) = val;
        }
}

// ---------------- out projection v2: fragment-major, LDS-free ----------------
__global__ __launch_bounds__(256, 2) void k_out(
    const unsigned short* __restrict__ attnF, const unsigned short* __restrict__ woF,
    const float* __restrict__ bias, float* __restrict__ out) {
    int wave = threadIdx.x >> 6, lane = threadIdx.x & 63;
    int l31 = lane & 31, hi = lane >> 5;
    int W = blockIdx.x * 4 + wave;   // 0..1535
    int nb = W / 6, cb = W % 6;      // 256 n-blocks x 6 c-blocks
    const unsigned short* A = attnF + (size_t)nb * 4096 * 8;
    const unsigned short* B = woF + (size_t)cb * 4096 * 8;

    f32x16 acc;
    #pragma unroll
    for (int r = 0; r < 16; r++) acc[r] = 0.f;
    #pragma unroll 16
    for (int kc = 0; kc < 64; kc++) {
        bf16x8 a = *(const bf16x8*)(A + ((kc * 2 + hi) * 32 + l31) * 8);
        bf16x8 b = *(const bf16x8*)(B + ((kc * 2 + hi) * 32 + l31) * 8);
        acc = __builtin_amdgcn_mfma_f32_32x32x16_bf16(a, b, acc, 0, 0, 0);
    }
    float bi = bias[cb * 32 + l31];
    #pragma unroll
    for (int r = 0; r < 16; r++) {
        int n = nb * 32 + (r & 3) + 8 * (r >> 2) + 4 * hi;
        out[(size_t)n * DIM + cb * 32 + l31] = acc[r] + bi;
    }
}

extern "C" void kernel_launch(void* const* d_in, const int* in_sizes, int n_in,
                              void* d_out, int out_size, void* d_ws, size_t ws_size,
                              hipStream_t stream) {
    const float* x     = (const float*)d_in[0];
    const float* shift = (const float*)d_in[1];
    const float* scale = (const float*)d_in[2];
    const float* nw    = (const float*)d_in[3];
    const float* nbv   = (const float*)d_in[4];
    const float* wqkv  = (const float*)d_in[5];
    const float* wout  = (const float*)d_in[6];
    const float* bout  = (const float*)d_in[7];
    float* out = (float*)d_out;

    char* ws = (char*)d_ws;
    unsigned short* hF    = (unsigned short*)(ws + 0);
    unsigned short* wF    = (unsigned short*)(ws + 3145728);
    unsigned short* woF   = (unsigned short*)(ws + 3145728 + 1179648);
    unsigned short* qm    = (unsigned short*)(ws + 4718592);
    unsigned short* km    = (unsigned short*)(ws + 4718592 + 16777216);
    unsigned short* vtm   = (unsigned short*)(ws + 4718592 + 2 * 16777216);
    unsigned short* attnF = (unsigned short*)(ws + 4718592 + 3 * 16777216);

    k_pre<<<dim3(5120), dim3(256), 0, stream>>>(x, shift, scale, nw, nbv, wqkv, wout, hF, wF, woF);
    k_qkv<<<dim3(48, 64), dim3(256), 0, stream>>>(hF, wF, qm, km, vtm);
    k_attn<<<dim3(128, 4), dim3(512), 0, stream>>>(qm, km, vtm, attnF);
    k_out<<<dim3(384), dim3(256), 0, stream>>>(attnF, woF, bout, out);
}